// Round 5
// baseline (5158.486 us; speedup 1.0000x reference)
//
#include <hip/hip_runtime.h>
#include <math.h>

#define IN_DIM 1024
#define E_DIM  256
#define N_EXP  512
#define N_TOK  131072   // 64 * 2048
#define TM     32       // tokens per block
#define BK     16       // k-chunk for GEMM1 (double-buffered)
#define NT     64       // IN_DIM / BK
#define BUF_BYTES 18432 // (512 + 4096) floats * 4
#define PJ_STR 17       // doubles per projn row (bank-conflict-free: 136B stride)
#define PJ_BYTES (E_DIM * PJ_STR * 8)   // 34,816
#define SMEM_BYTES 36864                // 2 staging bufs; >= PJ_BYTES + cand(2KB)

typedef double d4 __attribute__((ext_vector_type(4)));

__device__ __forceinline__ void ins2(double v, int c,
                                     double& v1, int& i1, double& v2, int& i2)
{
    if (v > v1 || (v == v1 && c < i1)) { v2 = v1; i2 = i1; v1 = v; i1 = c; }
    else if (v > v2 || (v == v2 && c < i2)) { v2 = v; i2 = c; }
}

// async global->LDS, 16B per lane, zero VGPR data movement
__device__ __forceinline__ void gload_lds16(const float* g, float* l)
{
    __builtin_amdgcn_global_load_lds(
        (const __attribute__((address_space(1))) unsigned int*)(g),
        (__attribute__((address_space(3))) unsigned int*)(l),
        16, 0, 0);
}

// ---------------------------------------------------------------------------
// Kernel A: L2-normalize center rows in fp64, write TRANSPOSED: cTd[k][ctr]
// ---------------------------------------------------------------------------
__global__ __launch_bounds__(64) void center_norm_kernel(
    const float* __restrict__ centers, double* __restrict__ cTd)
{
    const int ctr  = blockIdx.x;   // 0..511
    const int lane = threadIdx.x;  // 0..63
    const float* row = centers + (size_t)ctr * E_DIM;
    double v[4];
    double s = 0.0;
#pragma unroll
    for (int i = 0; i < 4; ++i) { v[i] = (double)row[lane + 64 * i]; s = fma(v[i], v[i], s); }
#pragma unroll
    for (int off = 32; off >= 1; off >>= 1) s += __shfl_xor(s, off, 64);
    const double inv = 1.0 / fmax(sqrt(s), 1e-12);
#pragma unroll
    for (int i = 0; i < 4; ++i)
        cTd[(size_t)(lane + 64 * i) * N_EXP + ctr] = v[i] * inv;
}

// ---------------------------------------------------------------------------
// Kernel B: fused fp64-accurate router on the f64 matrix pipe.
// 256 threads = 4 waves. GEMM1: wave wv owns expert cols [64wv,64wv+64),
// async global_load_lds double-buffer (BK=16). GEMM2 is TOKEN-SPLIT into two
// 16-token halves so projn is [256][17] f64 = 34.8KB -> static LDS 36,864B
// -> 4 blocks/CU (16 waves) instead of 2.
// mfma_f64_16x16x4 layouts: A[row=l&15][k=l>>4], B[k=l>>4][col=l&15],
// D[row=(l>>4)*4+i][col=l&15].
// projn stride 17 doubles: writes at b128 floor (8/bank), reads at b64 floor
// (4/bank) -> conflict-free. K accumulation order identical to prior rounds.
// ---------------------------------------------------------------------------
__global__ __launch_bounds__(256, 2) void router_kernel(
    const float* __restrict__ x, const float* __restrict__ W,
    const float* __restrict__ bias, const double* __restrict__ cTd,
    float* __restrict__ out)
{
    __shared__ __align__(16) char smem_raw[SMEM_BYTES];
    const int tid  = threadIdx.x;
    const int lane = tid & 63;
    const int wv   = tid >> 6;     // wave 0..3
    const int r    = lane & 15;    // frag row/col
    const int q    = lane >> 4;    // frag k-slot / row-group
    const int tokBase = blockIdx.x * TM;

    // --- GEMM1 staging geometry (per-lane, constant) -----------------------
    // f4 slot s = p*256 + wv*64 + lane -> row = s>>2, physical f4 col = s&3.
    // Stored value = global f4 col (s&3) ^ ((row>>1)&3) = (lane&3)^((lane>>3)&3).
    const int srow = lane >> 2;                        // 0..15
    const int scol = (lane & 3) ^ ((lane >> 3) & 3);   // pre-swizzled f4 col
    const float* xg = x + (size_t)(tokBase + (wv & 1) * 16 + srow) * IN_DIM + scol * 4; // wv<2 only
    const float* wg = W + (size_t)(wv * 16 + srow) * IN_DIM + scol * 4;

    d4 acc[2][4];                                      // [token-half][n-frag]
#pragma unroll
    for (int m = 0; m < 2; ++m)
#pragma unroll
        for (int n = 0; n < 4; ++n) acc[m][n] = (d4){0.0, 0.0, 0.0, 0.0};

    // read-side swizzle: logical (row, f4col kk) lives at f4col kk^((row>>1)&3);
    // all rows touched by this lane share (row>>1)&3 == (r>>1)&3.
    const int swz   = (r >> 1) & 3;
    const int abase = r * 16 + q;                 // x float offset (row r)
    const int bbase = (wv * 64 + r) * 16 + q;     // W float offset (row wv*64+r)

    // ---------------- GEMM1 (f64 MFMA, async double-buffered) --------------
    {   // prologue: stage tile 0 into buffer 0
        float* b = (float*)smem_raw;
        if (wv < 2) gload_lds16(xg, b + wv * 256);
#pragma unroll
        for (int p = 0; p < 4; ++p)
            gload_lds16(wg + (size_t)p * 64 * IN_DIM, b + 512 + p * 1024 + wv * 256);
    }
    __syncthreads();   // implicit vmcnt(0) drain: tile 0 resident

    int cur = 0;
    for (int t = 0; t < NT; ++t) {
        if (t + 1 < NT) {   // issue next-tile DMA; lands during MFMA phase
            float* b = (float*)(smem_raw + (cur ^ 1) * BUF_BYTES);
            const int k0 = (t + 1) * BK;
            if (wv < 2) gload_lds16(xg + k0, b + wv * 256);
#pragma unroll
            for (int p = 0; p < 4; ++p)
                gload_lds16(wg + (size_t)p * 64 * IN_DIM + k0, b + 512 + p * 1024 + wv * 256);
        }
        const float* xb = (const float*)(smem_raw + cur * BUF_BYTES);
        const float* wb = xb + 512;
#pragma unroll
        for (int kk = 0; kk < 4; ++kk) {
            const int so = 4 * (kk ^ swz);
            const double a0 = (double)xb[abase + so];          // tokens 0..15
            const double a1 = (double)xb[abase + 256 + so];    // tokens 16..31
#pragma unroll
            for (int n = 0; n < 4; ++n) {
                const double b = (double)wb[bbase + n * 256 + so];
                acc[0][n] = __builtin_amdgcn_mfma_f64_16x16x4f64(a0, b, acc[0][n], 0, 0, 0);
                acc[1][n] = __builtin_amdgcn_mfma_f64_16x16x4f64(a1, b, acc[1][n], 0, 0, 0);
            }
        }
        __syncthreads();   // vmcnt(0)+barrier: next tile resident, reads done
        cur ^= 1;
    }

    // ---------------- bias (fp64) --------------------------------------------
#pragma unroll
    for (int n = 0; n < 4; ++n) {
        const double bb = (double)bias[wv * 64 + n * 16 + r];
#pragma unroll
        for (int m = 0; m < 2; ++m)
#pragma unroll
            for (int i = 0; i < 4; ++i) acc[m][n][i] += bb;
    }

    // ---------------- per-token L2 norm (cross-wave via LDS, off-projn) ------
    double* partials = (double*)(smem_raw + PJ_BYTES);   // [4 waves][32 tok] = 1KB
    double ss[2][4];
#pragma unroll
    for (int m = 0; m < 2; ++m)
#pragma unroll
        for (int i = 0; i < 4; ++i) {
            double s = 0.0;
#pragma unroll
            for (int n = 0; n < 4; ++n) s = fma(acc[m][n][i], acc[m][n][i], s);
#pragma unroll
            for (int off = 8; off >= 1; off >>= 1) s += __shfl_xor(s, off, 64);
            ss[m][i] = s;
        }
    if (r == 0) {
#pragma unroll
        for (int m = 0; m < 2; ++m)
#pragma unroll
            for (int i = 0; i < 4; ++i)
                partials[wv * 32 + m * 16 + q * 4 + i] = ss[m][i];
    }
    __syncthreads();

    double inv[2][4];
#pragma unroll
    for (int m = 0; m < 2; ++m)
#pragma unroll
        for (int i = 0; i < 4; ++i) {
            const int t = m * 16 + q * 4 + i;
            const double s = partials[t] + partials[32 + t] + partials[64 + t] + partials[96 + t];
            inv[m][i] = 1.0 / fmax(sqrt(s), 1e-12);
        }
    // NOTE: no extra sync needed before projn writes — projn region [0,PJ_BYTES)
    // is the dead GEMM1 staging area; partials live above it.

    double* projn = (double*)smem_raw;                    // [256][PJ_STR]
    double* cand  = (double*)(smem_raw + PJ_BYTES);       // [4 waves][16 tok][4] = 2KB

    // ================= token-split halves: 16 tokens each ====================
    for (int h = 0; h < 2; ++h) {
        __syncthreads();   // h0: partials reads done; h1: GEMM2(h0) projn reads
                           // + cand(h0) reads done before overwrite

        // write NORMALIZED projn[e][tok16] for this half
#pragma unroll
        for (int n = 0; n < 4; ++n)
#pragma unroll
            for (int i = 0; i < 4; ++i)
                projn[(wv * 64 + n * 16 + r) * PJ_STR + q * 4 + i] = acc[h][n][i] * inv[h][i];
        __syncthreads();

        // ---------------- GEMM2 (f64 MFMA) + fused per-lane top-2 ------------
        double tv1[4], tv2[4];
        int    ti1[4], ti2[4];
#pragma unroll
        for (int i = 0; i < 4; ++i) { tv1[i] = -1e300; tv2[i] = -1e300; ti1[i] = 0; ti2[i] = 0; }

        for (int pass = 0; pass < 2; ++pass) {
            const int colbase = wv * 128 + pass * 64;
            d4 acc2[4];
#pragma unroll
            for (int n = 0; n < 4; ++n) acc2[n] = (d4){0.0, 0.0, 0.0, 0.0};

            const double* pa = projn + q * PJ_STR + r;          // A from LDS
            const double* cb = cTd + (size_t)q * N_EXP + colbase + r;  // B from L2
#pragma unroll 4
            for (int kk = 0; kk < 64; ++kk) {
                const double a = pa[0];
#pragma unroll
                for (int n = 0; n < 4; ++n) {
                    const double b = cb[n * 16];
                    acc2[n] = __builtin_amdgcn_mfma_f64_16x16x4f64(a, b, acc2[n], 0, 0, 0);
                }
                pa += 4 * PJ_STR;
                cb += (size_t)4 * N_EXP;
            }
#pragma unroll
            for (int i = 0; i < 4; ++i)
#pragma unroll
                for (int n = 0; n < 4; ++n)
                    ins2(acc2[n][i], colbase + n * 16 + r,
                         tv1[i], ti1[i], tv2[i], ti2[i]);
        }

        // merge top-2 across the 16 col-lanes of each token row
#pragma unroll
        for (int i = 0; i < 4; ++i) {
#pragma unroll
            for (int off = 8; off >= 1; off >>= 1) {
                const double ov1 = __shfl_xor(tv1[i], off, 64);
                const int    oi1 = __shfl_xor(ti1[i], off, 64);
                const double ov2 = __shfl_xor(tv2[i], off, 64);
                const int    oi2 = __shfl_xor(ti2[i], off, 64);
                ins2(ov1, oi1, tv1[i], ti1[i], tv2[i], ti2[i]);
                ins2(ov2, oi2, tv1[i], ti1[i], tv2[i], ti2[i]);
            }
        }

        __syncthreads();   // GEMM2 reads done; cand region (== partials) free
        if (r == 0) {
#pragma unroll
            for (int i = 0; i < 4; ++i) {
                double* cd = cand + ((wv * 16 + q * 4 + i) << 2);
                cd[0] = tv1[i]; cd[1] = (double)ti1[i];
                cd[2] = tv2[i]; cd[3] = (double)ti2[i];
            }
        }
        __syncthreads();

        if (tid < 16) {
            double v1 = -1e300, v2 = -1e300;
            int    i1 = 0, i2 = 0;
            for (int s = 0; s < 4; ++s) {
                const double* cd = cand + ((s * 16 + tid) << 2);
                ins2(cd[0], (int)cd[1], v1, i1, v2, i2);
                ins2(cd[2], (int)cd[3], v1, i1, v2, i2);
            }
            const double e  = exp(v2 - v1);    // <= 1
            const double dn = 1.0 + e;
            const size_t g  = (size_t)tokBase + h * 16 + tid;
            out[g * 2 + 0] = (float)(1.0 / dn);
            out[g * 2 + 1] = (float)(e / dn);
            out[(size_t)2 * N_TOK + g * 2 + 0] = (float)i1;
            out[(size_t)2 * N_TOK + g * 2 + 1] = (float)i2;
        }
    }
}

// ---------------------------------------------------------------------------
extern "C" void kernel_launch(void* const* d_in, const int* in_sizes, int n_in,
                              void* d_out, int out_size, void* d_ws, size_t ws_size,
                              hipStream_t stream)
{
    const float* x       = (const float*)d_in[0];
    const float* W       = (const float*)d_in[1];
    const float* bias    = (const float*)d_in[2];
    const float* centers = (const float*)d_in[3];
    // d_in[4] = top_k (always 2, hard-coded)
    double* cTd = (double*)d_ws;   // 256 x 512 doubles = 1 MB scratch
    float*  out = (float*)d_out;

    center_norm_kernel<<<N_EXP, 64, 0, stream>>>(centers, cTd);
    router_kernel<<<N_TOK / TM, 256, 0, stream>>>(x, W, bias, cTd, out);
}